// Round 2
// baseline (884.815 us; speedup 1.0000x reference)
//
#include <hip/hip_runtime.h>

// ---------------------------------------------------------------------------
// 2-layer GCN: out = A_norm @ relu(A_norm @ (x@W1) + b1) @ W2 (+b2)
// A_norm = D^-1/2 (A+I) D^-1/2, factored: out[d] = dinv[d]*sum_src(g[src]) + b
// with g = dinv * (x @ W).
//
// R1: two-level counting-sort CSR build (killed 198 MB scatter-write amp).
// R2: G stored bf16 (aggregate is L3-fetch-bound; halve the payload).
// R3/R4: MFMA bf16 GEMM (split-A ~f32 precision), packed 4 B pairs, bf16 act.
// R5: radix CSR (single-pass partition); gemm1 direct-from-global A-frags.
// R6: FAILED fusion of agg1+gemm2 (barrier serialization). R7 reverted.
// R7: unfused agg1(bf16 out) + gemm2 (direct global loads, in-place act->G2).
// R8: channel-chunked gather. G1/act/G2 stored [8][N][16] bf16 (chunk-major).
//     Aggregates run 8 passes (gridDim.y = chunk, slow-varying): per-pass
//     gather table = 3.2 MB < 4 MB per-XCD L2 -> gathers become L2 hits;
//     miss path carries ~compulsory traffic only (was 361 MB @ 3.28 TB/s =
//     the bottleneck). Per edge still exactly 1 L2 txn (16 edges/wave-instr,
//     4 lanes x 8 B each). NB = ceil(N/4) = 25000 is 8-aligned -> node->XCD
//     mapping consistent across passes (srcs slice can stay L2-resident).
//     (R8b: nontemporal_store needs clang ext-vector, not HIP float4.)
// Requires N <= 131072 (17-bit src in packed pairs).
// ---------------------------------------------------------------------------

#define NPB 128          // nodes per bucket (dst >> 7)
#define NBMAX 1024       // supports N <= 131072
#define EPT 64           // edges per thread in partition/hist kernels
#define PART_TILE (256 * EPT)
#define NCHUNK 8         // 128 channels / 16 per chunk

typedef unsigned short ushort_t;
typedef unsigned long long ull_t;
typedef __attribute__((ext_vector_type(8))) short short8;
typedef __attribute__((ext_vector_type(4))) float f32x4;

__device__ __forceinline__ unsigned short f32_to_bf16_rne(float x) {
    unsigned int v = __float_as_uint(x);
    unsigned int r = v + 0x7fffu + ((v >> 16) & 1u);
    return (unsigned short)(r >> 16);
}

// W (f32, [k][n]) -> Wprep (bf16, [n][k]) for both layers. 2*16384 elems.
__global__ __launch_bounds__(256) void k_wprep(
    const float* __restrict__ W1, const float* __restrict__ W2,
    ushort_t* __restrict__ Wp1, ushort_t* __restrict__ Wp2) {
    int idx = blockIdx.x * 256 + threadIdx.x;
    int which = idx >> 14;
    int e = idx & 16383;
    int n = e & 127, k = e >> 7;
    const float* W = which ? W2 : W1;
    ushort_t* Wp = which ? Wp2 : Wp1;
    Wp[n * 128 + k] = f32_to_bf16_rne(W[k * 128 + n]);
}

// Radix pass 0: per-tile bucket histogram -> C[tile][b].
__global__ __launch_bounds__(256) void k_hist_tiles(
    const int* __restrict__ dst, int* __restrict__ C,
    int e, int nbp, int total) {
    __shared__ int hist[NBMAX];
    int t = threadIdx.x;
    int tile = blockIdx.x;
    for (int k = t; k < nbp; k += 256) hist[k] = 0;
    __syncthreads();
    int t0 = tile * PART_TILE;
#pragma unroll 4
    for (int j = 0; j < EPT; j++) {
        int i = t0 + j * 256 + t;
        if (i < total) {
            int d = (i < e) ? dst[i] : (i - e);
            atomicAdd(&hist[d >> 7], 1);
        }
    }
    __syncthreads();
    int* row = C + (size_t)tile * nbp;
    for (int k = t; k < nbp; k += 256) row[k] = hist[k];
}

// Radix pass 1: column-wise exclusive scan of C over tiles; colsum[b] = total.
__global__ __launch_bounds__(256) void k_col_scan(
    int* __restrict__ C, int* __restrict__ colsum, int T, int nbp) {
    int b = blockIdx.x * 256 + threadIdx.x;
    if (b >= nbp) return;
    int running = 0;
    int t = 0;
    for (; t + 8 <= T; t += 8) {
        int v[8];
#pragma unroll
        for (int j = 0; j < 8; j++) v[j] = C[(size_t)(t + j) * nbp + b];
#pragma unroll
        for (int j = 0; j < 8; j++) {
            C[(size_t)(t + j) * nbp + b] = running;
            running += v[j];
        }
    }
    for (; t < T; t++) {
        int v = C[(size_t)t * nbp + b];
        C[(size_t)t * nbp + b] = running;
        running += v;
    }
    colsum[b] = running;
}

// Exclusive scan of colsum -> bucket_ptr. 1 WG, nbp <= 1024.
__global__ __launch_bounds__(256) void k_bucket_scan(
    const int* __restrict__ colsum, int* __restrict__ bucket_ptr,
    int nbp, int total) {
    __shared__ int sd[256];
    int t = threadIdx.x;
    int c[4];
#pragma unroll
    for (int j = 0; j < 4; j++) {
        int k = t * 4 + j;
        c[j] = (k < nbp) ? colsum[k] : 0;
    }
    int s = c[0] + c[1] + c[2] + c[3];
    sd[t] = s;
    __syncthreads();
    for (int off = 1; off < 256; off <<= 1) {
        int v = (t >= off) ? sd[t - off] : 0;
        __syncthreads();
        sd[t] += v;
        __syncthreads();
    }
    int pre = sd[t] - s;
#pragma unroll
    for (int j = 0; j < 4; j++) {
        int k = t * 4 + j;
        if (k < nbp) bucket_ptr[k] = pre;
        pre += c[j];
    }
    if (t == 255) bucket_ptr[nbp] = total;
}

// Radix pass 2: single-pass partition. LDS cursor = C[tile][b] + bucket_ptr[b].
__global__ __launch_bounds__(256) void k_partition(
    const int* __restrict__ src, const int* __restrict__ dst,
    const int* __restrict__ C, const int* __restrict__ bucket_ptr,
    unsigned int* __restrict__ pairs, int e, int nbp, int total) {
    __shared__ int lcur[NBMAX];
    int t = threadIdx.x;
    int tile = blockIdx.x;
    const int* row = C + (size_t)tile * nbp;
    for (int k = t; k < nbp; k += 256) lcur[k] = row[k] + bucket_ptr[k];
    __syncthreads();
    int t0 = tile * PART_TILE;
#pragma unroll 4
    for (int j = 0; j < EPT; j++) {
        int i = t0 + j * 256 + t;
        if (i < total) {
            int s, d;
            if (i < e) { s = src[i]; d = dst[i]; }
            else       { s = i - e;  d = s; }
            int b = d >> 7;
            int off = atomicAdd(&lcur[b], 1);
            pairs[off] = (unsigned int)s | ((unsigned int)(d & 127) << 17);
        }
    }
}

// Pass 3: one WG per bucket; LDS-only counts/scan/row_ptr/dinv/fine-sort.
__global__ __launch_bounds__(256) void k_build(
    const unsigned int* __restrict__ pairs, const int* __restrict__ bucket_ptr,
    int* __restrict__ row_ptr, int* __restrict__ srcs,
    float* __restrict__ dinv, int n) {
    __shared__ int cnt[NPB];
    __shared__ int scn[NPB];
    __shared__ int cur[NPB];
    int b = blockIdx.x;
    int t = threadIdx.x;
    int node0 = b << 7;
    int p0 = bucket_ptr[b], p1 = bucket_ptr[b + 1];
    if (t < NPB) cnt[t] = 0;
    __syncthreads();
    for (int i = p0 + t; i < p1; i += 256) {
        int dlow = (int)(pairs[i] >> 17) & 127;
        atomicAdd(&cnt[dlow], 1);
    }
    __syncthreads();
    if (t < NPB) scn[t] = cnt[t];
    __syncthreads();
    for (int off = 1; off < NPB; off <<= 1) {
        int v = (t < NPB && t >= off) ? scn[t - off] : 0;
        __syncthreads();
        if (t < NPB) scn[t] += v;
        __syncthreads();
    }
    if (t < NPB) {
        int incl = scn[t];
        int excl = incl - cnt[t];
        int start = p0 + excl;
        cur[t] = start;
        int node = node0 + t;
        if (node < n) {
            row_ptr[node] = start;
            dinv[node] = rsqrtf((float)cnt[t]);  // deg >= 1 (self-loop)
            if (node == n - 1) row_ptr[n] = p0 + incl;
        }
    }
    __syncthreads();
    for (int i = p0 + t; i < p1; i += 256) {
        unsigned int pr = pairs[i];
        int pos = atomicAdd(&cur[(pr >> 17) & 127], 1);
        srcs[pos] = (int)(pr & 0x1FFFFu);
    }
}

// ---------------------------------------------------------------------------
// GEMM1: G[c][r][16] = bf16( dinv[r] * (A @ W)[r][c*16..] ), A: Mx128 f32.
// Chunk-major output: chunk index == c (channel block). Split-A bf16 MFMA.
// mfma_f32_16x16x32_bf16 layouts (HW-verified, guide m89/m91):
//   A: lane holds A[m=lane&15][k=(lane>>4)*8 + j]
//   B: lane holds B[k=(lane>>4)*8 + j][n=lane&15]   (Wp is [n][k] bf16)
//   C/D: col=lane&15, row=(lane>>4)*4 + reg
// ---------------------------------------------------------------------------
__global__ __launch_bounds__(256) void k_gemm1(
    const float* __restrict__ A, const ushort_t* __restrict__ Wp,
    const float* __restrict__ dinv, ushort_t* __restrict__ G, int M) {
    int t = threadIdx.x;
    int row0 = blockIdx.x * 64;
    int wv = t >> 6;
    int lane = t & 63;
    int m = lane & 15;
    int quad = lane >> 4;

    int gr_row = row0 + wv * 16 + m;
    int gcl = gr_row < M ? gr_row : M - 1;
    const float* ap = A + (size_t)gcl * 128 + quad * 8;

    f32x4 acc[8];
#pragma unroll
    for (int c = 0; c < 8; c++) acc[c] = (f32x4){0.f, 0.f, 0.f, 0.f};

#pragma unroll
    for (int ks = 0; ks < 4; ks++) {
        int kb = ks * 32 + quad * 8;
        float xs[8];
        *(float4*)&xs[0] = *(const float4*)(ap + ks * 32);
        *(float4*)&xs[4] = *(const float4*)(ap + ks * 32 + 4);
        short8 ahi, alo;
#pragma unroll
        for (int j = 0; j < 8; j++) {
            unsigned short h = f32_to_bf16_rne(xs[j]);
            ahi[j] = (short)h;
            float hf = __uint_as_float((unsigned int)h << 16);
            alo[j] = (short)f32_to_bf16_rne(xs[j] - hf);
        }
#pragma unroll
        for (int c = 0; c < 8; c++) {
            short8 b8 = *(const short8*)(Wp + (size_t)(c * 16 + m) * 128 + kb);
            acc[c] = __builtin_amdgcn_mfma_f32_16x16x32_bf16(ahi, b8, acc[c], 0, 0, 0);
            acc[c] = __builtin_amdgcn_mfma_f32_16x16x32_bf16(alo, b8, acc[c], 0, 0, 0);
        }
    }

    int rbase = row0 + wv * 16 + quad * 4;
#pragma unroll
    for (int reg = 0; reg < 4; reg++) {
        int gr = rbase + reg;
        if (gr < M) {
            float dv = dinv[gr];
#pragma unroll
            for (int c = 0; c < 8; c++)
                G[((size_t)c * M + gr) * 16 + m] = f32_to_bf16_rne(acc[c][reg] * dv);
        }
    }
}

// ---------------------------------------------------------------------------
// GEMM2: in-place actG2[c][r][16] = bf16( dinv[r] * (act @ W2)[r][c*16..] ).
// act rows are wave-private (block = 64 rows, wave = 16 rows); in a wave all
// A-loads complete (MFMA data dep) before epilogue stores -> in-place is safe.
// Clamped tail rows may read racing data but their results are discarded.
// NOTE: actG2 deliberately NOT __restrict__ (true aliasing).
// ---------------------------------------------------------------------------
__global__ __launch_bounds__(256) void k_gemm2(
    ushort_t* actG2, const ushort_t* __restrict__ Wp,
    const float* __restrict__ dinv, int M) {
    int t = threadIdx.x;
    int row0 = blockIdx.x * 64;
    int wv = t >> 6;
    int lane = t & 63;
    int m = lane & 15;
    int quad = lane >> 4;

    int gr_row = row0 + wv * 16 + m;
    int gcl = gr_row < M ? gr_row : M - 1;

    f32x4 acc[8];
#pragma unroll
    for (int c = 0; c < 8; c++) acc[c] = (f32x4){0.f, 0.f, 0.f, 0.f};

#pragma unroll
    for (int ks = 0; ks < 4; ks++) {
        int kb = ks * 32 + quad * 8;
        // chunked act: channels kb..kb+7 live in chunk kb>>4 at offset kb&15
        short8 a8 = *(const short8*)(actG2 + ((size_t)(kb >> 4) * M + gcl) * 16 + (kb & 15));
#pragma unroll
        for (int c = 0; c < 8; c++) {
            short8 b8 = *(const short8*)(Wp + (size_t)(c * 16 + m) * 128 + kb);
            acc[c] = __builtin_amdgcn_mfma_f32_16x16x32_bf16(a8, b8, acc[c], 0, 0, 0);
        }
    }

    int rbase = row0 + wv * 16 + quad * 4;
#pragma unroll
    for (int reg = 0; reg < 4; reg++) {
        int gr = rbase + reg;
        if (gr < M) {
            float dv = dinv[gr];
#pragma unroll
            for (int c = 0; c < 8; c++)
                actG2[((size_t)c * M + gr) * 16 + m] = f32_to_bf16_rne(acc[c][reg] * dv);
        }
    }
}

// ---------------------------------------------------------------------------
// Chunked aggregates. gridDim.y = chunk (slow-varying in dispatch order ->
// temporal separation; per-pass table = N*32 B = 3.2 MB, L2-resident/XCD).
// Wave = 1 node. Per 16-edge group: 4 lanes/edge, 8 B (4 ch) per lane ->
// one wave-instr = 16 edges = 16 L2 segments (1 txn/edge, same as full-row).
// Reduce over edge slots with shfl_xor strides 4..32; lanes 0-3 store 16 ch.
// ---------------------------------------------------------------------------

// Aggregate 1: act[chunk][wid][16] = bf16(relu(dinv*sum(G1[src]) + b1)).
__global__ __launch_bounds__(256) void k_agg1(
    const int* __restrict__ row_ptr, const int* __restrict__ srcs,
    const ushort_t* __restrict__ G, const float* __restrict__ dinv,
    const float* __restrict__ bias, ull_t* __restrict__ ActOut, int n) {
    int chunk = blockIdx.y;
    int wid = (blockIdx.x * 256 + threadIdx.x) >> 6;
    int lane = threadIdx.x & 63;
    if (wid >= n) return;
    int beg = row_ptr[wid], end = row_ptr[wid + 1];
    int g = lane >> 2;   // edge slot 0..15
    int q = lane & 3;    // channel quad (4 ch = 8 B)
    const ull_t* T = (const ull_t*)(G + (size_t)chunk * n * 16);
    float a0 = 0.f, a1 = 0.f, a2 = 0.f, a3 = 0.f;
    for (int p = beg; p < end; p += 32) {
#pragma unroll
        for (int j = 0; j < 2; j++) {
            int g0 = p + j * 16;
            if (g0 < end) {                 // wave-uniform group predicate
                int eidx = g0 + g;
                bool ok = eidx < end;
                int s = srcs[ok ? eidx : end - 1];
                ull_t u = T[(size_t)s * 4 + q];
                if (!ok) u = 0ull;
                unsigned int u0 = (unsigned int)u, u1 = (unsigned int)(u >> 32);
                a0 += __uint_as_float(u0 << 16);
                a1 += __uint_as_float(u0 & 0xffff0000u);
                a2 += __uint_as_float(u1 << 16);
                a3 += __uint_as_float(u1 & 0xffff0000u);
            }
        }
    }
#pragma unroll
    for (int off = 4; off < 64; off <<= 1) {
        a0 += __shfl_xor(a0, off);
        a1 += __shfl_xor(a1, off);
        a2 += __shfl_xor(a2, off);
        a3 += __shfl_xor(a3, off);
    }
    if (g == 0) {
        float dv = dinv[wid];
        const float* bp = bias + chunk * 16 + q * 4;
        a0 = fmaxf(fmaf(a0, dv, bp[0]), 0.f);
        a1 = fmaxf(fmaf(a1, dv, bp[1]), 0.f);
        a2 = fmaxf(fmaf(a2, dv, bp[2]), 0.f);
        a3 = fmaxf(fmaf(a3, dv, bp[3]), 0.f);
        unsigned int p0 = (unsigned int)f32_to_bf16_rne(a0) |
                          ((unsigned int)f32_to_bf16_rne(a1) << 16);
        unsigned int p1 = (unsigned int)f32_to_bf16_rne(a2) |
                          ((unsigned int)f32_to_bf16_rne(a3) << 16);
        ull_t uo = (ull_t)p0 | ((ull_t)p1 << 32);
        __builtin_nontemporal_store(uo, ActOut + ((size_t)chunk * n + wid) * 4 + q);
    }
}

// Aggregate 2: out[wid][chunk*16..] = dinv*sum(G2[src]) + b2 (f32, nt store).
__global__ __launch_bounds__(256) void k_agg2(
    const int* __restrict__ row_ptr, const int* __restrict__ srcs,
    const ushort_t* __restrict__ G, const float* __restrict__ dinv,
    const float* __restrict__ bias, float* __restrict__ Out, int n) {
    int chunk = blockIdx.y;
    int wid = (blockIdx.x * 256 + threadIdx.x) >> 6;
    int lane = threadIdx.x & 63;
    if (wid >= n) return;
    int beg = row_ptr[wid], end = row_ptr[wid + 1];
    int g = lane >> 2;
    int q = lane & 3;
    const ull_t* T = (const ull_t*)(G + (size_t)chunk * n * 16);
    float a0 = 0.f, a1 = 0.f, a2 = 0.f, a3 = 0.f;
    for (int p = beg; p < end; p += 32) {
#pragma unroll
        for (int j = 0; j < 2; j++) {
            int g0 = p + j * 16;
            if (g0 < end) {
                int eidx = g0 + g;
                bool ok = eidx < end;
                int s = srcs[ok ? eidx : end - 1];
                ull_t u = T[(size_t)s * 4 + q];
                if (!ok) u = 0ull;
                unsigned int u0 = (unsigned int)u, u1 = (unsigned int)(u >> 32);
                a0 += __uint_as_float(u0 << 16);
                a1 += __uint_as_float(u0 & 0xffff0000u);
                a2 += __uint_as_float(u1 << 16);
                a3 += __uint_as_float(u1 & 0xffff0000u);
            }
        }
    }
#pragma unroll
    for (int off = 4; off < 64; off <<= 1) {
        a0 += __shfl_xor(a0, off);
        a1 += __shfl_xor(a1, off);
        a2 += __shfl_xor(a2, off);
        a3 += __shfl_xor(a3, off);
    }
    if (g == 0) {
        float dv = dinv[wid];
        const float* bp = bias + chunk * 16 + q * 4;
        f32x4 o;
        o.x = fmaf(a0, dv, bp[0]);
        o.y = fmaf(a1, dv, bp[1]);
        o.z = fmaf(a2, dv, bp[2]);
        o.w = fmaf(a3, dv, bp[3]);
        __builtin_nontemporal_store(o,
            (f32x4*)(Out + (size_t)wid * 128 + chunk * 16 + q * 4));
    }
}

extern "C" void kernel_launch(void* const* d_in, const int* in_sizes, int n_in,
                              void* d_out, int out_size, void* d_ws, size_t ws_size,
                              hipStream_t stream) {
    const float* x  = (const float*)d_in[0];
    const int*   ei = (const int*)d_in[1];
    const float* W1 = (const float*)d_in[2];
    const float* b1 = (const float*)d_in[3];
    const float* W2 = (const float*)d_in[4];
    const float* b2 = (const float*)d_in[5];
    float* out = (float*)d_out;

    const int C = 128;
    const int N = in_sizes[0] / C;
    const int E = in_sizes[1] / 2;
    const int* src = ei;
    const int* dst = ei + E;
    const int total = E + N;
    const int nbp = (N + NPB - 1) >> 7;                 // buckets (782)
    const int T = (total + PART_TILE - 1) / PART_TILE;  // tiles (202)

    char* ws = (char*)d_ws;
    size_t off = 0;
    auto alloc = [&](size_t bytes) -> void* {
        void* p = ws + off;
        off = (off + bytes + 511) & ~(size_t)511;
        return p;
    };
    int*   Cmat       = (int*)alloc((size_t)T * nbp * 4);       // ~632 KB
    int*   colsum     = (int*)alloc((size_t)nbp * 4);
    int*   bucket_ptr = (int*)alloc((size_t)(nbp + 1) * 4);
    int*   row_ptr    = (int*)alloc(((size_t)N + 1) * 4);
    float* dinv       = (float*)alloc((size_t)N * 4);
    int*   srcs       = (int*)alloc((size_t)total * 4);
    ushort_t* Wp1     = (ushort_t*)alloc(128 * 128 * 2);
    ushort_t* Wp2     = (ushort_t*)alloc(128 * 128 * 2);
    ushort_t* G1      = (ushort_t*)alloc((size_t)N * C * 2);
    // act/G2 (in-place, N*C*2) shares with pairs (total*4): pairs dead
    // after k_build, act written by k_agg1 afterwards.
    size_t ab = (size_t)N * C * 2, pb = (size_t)total * 4;
    void* shared = alloc(ab > pb ? ab : pb);
    ushort_t* actG2 = (ushort_t*)shared;
    unsigned int* pairs = (unsigned int*)shared;

    // ---- weight prep + radix CSR build ----
    k_wprep<<<128, 256, 0, stream>>>(W1, W2, Wp1, Wp2);
    k_hist_tiles<<<T, 256, 0, stream>>>(dst, Cmat, E, nbp, total);
    k_col_scan<<<(nbp + 255) / 256, 256, 0, stream>>>(Cmat, colsum, T, nbp);
    k_bucket_scan<<<1, 256, 0, stream>>>(colsum, bucket_ptr, nbp, total);
    k_partition<<<T, 256, 0, stream>>>(src, dst, Cmat, bucket_ptr, pairs, E, nbp, total);
    k_build<<<nbp, 256, 0, stream>>>(pairs, bucket_ptr, row_ptr, srcs, dinv, N);

    const int NB = (N + 3) / 4;           // node-blocks per chunk pass (25000)
    dim3 agrid(NB, NCHUNK);

    // ---- layer 1: G1[c][r][16] = bf16(dinv*(x@W1)); act chunked bf16 ----
    k_gemm1<<<(N + 63) / 64, 256, 0, stream>>>(x, Wp1, dinv, G1, N);
    k_agg1<<<agrid, 256, 0, stream>>>(row_ptr, srcs, G1, dinv, b1,
                                      (ull_t*)actG2, N);

    // ---- layer 2: G2 = bf16(dinv*(act@W2)) in-place chunked; out = dinv*sum+b2 ----
    k_gemm2<<<(N + 63) / 64, 256, 0, stream>>>(actG2, Wp2, dinv, N);
    k_agg2<<<agrid, 256, 0, stream>>>(row_ptr, srcs, actG2, dinv, b2, out, N);
}

// Round 3
// 756.482 us; speedup vs baseline: 1.1696x; 1.1696x over previous
//
#include <hip/hip_runtime.h>

// ---------------------------------------------------------------------------
// 2-layer GCN: out = A_norm @ relu(A_norm @ (x@W1) + b1) @ W2 (+b2)
// A_norm = D^-1/2 (A+I) D^-1/2, factored: out[d] = dinv[d]*sum_src(g[src]) + b
// with g = dinv * (x @ W).
//
// R1: two-level counting-sort CSR build. R2: bf16 G. R3/R4: MFMA GEMM.
// R5: radix CSR. R6: FAILED fusion (reverted R7). R7: unfused, 519 us.
// R8: channel-chunked gather [8][N][16] bf16. FETCH hit compulsory floor
//     (361->202 MB) but dur 110->308 us: wave=node left ~2 gather instrs vs
//     ~110 overhead instrs per wave (shfl tree, tails) -> issue-bound.
// R9: keep chunk-major layout; restructure agg: wave = 16 consecutive nodes,
//     4 lanes/node (lane quad owns 4 channels), per-group serial edge walk
//     (exec-masked divergence), unroll-4, NO cross-lane reduce. ~0.75
//     wave-instr/edge-visit. Bound ~= compulsory fetch 205 MB @ 3.3 TB/s.
// Requires N <= 131072 (17-bit src in packed pairs).
// ---------------------------------------------------------------------------

#define NPB 128          // nodes per bucket (dst >> 7)
#define NBMAX 1024       // supports N <= 131072
#define EPT 64           // edges per thread in partition/hist kernels
#define PART_TILE (256 * EPT)
#define NCHUNK 8         // 128 channels / 16 per chunk

typedef unsigned short ushort_t;
typedef unsigned long long ull_t;
typedef __attribute__((ext_vector_type(8))) short short8;
typedef __attribute__((ext_vector_type(4))) float f32x4;

__device__ __forceinline__ unsigned short f32_to_bf16_rne(float x) {
    unsigned int v = __float_as_uint(x);
    unsigned int r = v + 0x7fffu + ((v >> 16) & 1u);
    return (unsigned short)(r >> 16);
}

// W (f32, [k][n]) -> Wprep (bf16, [n][k]) for both layers. 2*16384 elems.
__global__ __launch_bounds__(256) void k_wprep(
    const float* __restrict__ W1, const float* __restrict__ W2,
    ushort_t* __restrict__ Wp1, ushort_t* __restrict__ Wp2) {
    int idx = blockIdx.x * 256 + threadIdx.x;
    int which = idx >> 14;
    int e = idx & 16383;
    int n = e & 127, k = e >> 7;
    const float* W = which ? W2 : W1;
    ushort_t* Wp = which ? Wp2 : Wp1;
    Wp[n * 128 + k] = f32_to_bf16_rne(W[k * 128 + n]);
}

// Radix pass 0: per-tile bucket histogram -> C[tile][b].
__global__ __launch_bounds__(256) void k_hist_tiles(
    const int* __restrict__ dst, int* __restrict__ C,
    int e, int nbp, int total) {
    __shared__ int hist[NBMAX];
    int t = threadIdx.x;
    int tile = blockIdx.x;
    for (int k = t; k < nbp; k += 256) hist[k] = 0;
    __syncthreads();
    int t0 = tile * PART_TILE;
#pragma unroll 4
    for (int j = 0; j < EPT; j++) {
        int i = t0 + j * 256 + t;
        if (i < total) {
            int d = (i < e) ? dst[i] : (i - e);
            atomicAdd(&hist[d >> 7], 1);
        }
    }
    __syncthreads();
    int* row = C + (size_t)tile * nbp;
    for (int k = t; k < nbp; k += 256) row[k] = hist[k];
}

// Radix pass 1: column-wise exclusive scan of C over tiles; colsum[b] = total.
__global__ __launch_bounds__(256) void k_col_scan(
    int* __restrict__ C, int* __restrict__ colsum, int T, int nbp) {
    int b = blockIdx.x * 256 + threadIdx.x;
    if (b >= nbp) return;
    int running = 0;
    int t = 0;
    for (; t + 8 <= T; t += 8) {
        int v[8];
#pragma unroll
        for (int j = 0; j < 8; j++) v[j] = C[(size_t)(t + j) * nbp + b];
#pragma unroll
        for (int j = 0; j < 8; j++) {
            C[(size_t)(t + j) * nbp + b] = running;
            running += v[j];
        }
    }
    for (; t < T; t++) {
        int v = C[(size_t)t * nbp + b];
        C[(size_t)t * nbp + b] = running;
        running += v;
    }
    colsum[b] = running;
}

// Exclusive scan of colsum -> bucket_ptr. 1 WG, nbp <= 1024.
__global__ __launch_bounds__(256) void k_bucket_scan(
    const int* __restrict__ colsum, int* __restrict__ bucket_ptr,
    int nbp, int total) {
    __shared__ int sd[256];
    int t = threadIdx.x;
    int c[4];
#pragma unroll
    for (int j = 0; j < 4; j++) {
        int k = t * 4 + j;
        c[j] = (k < nbp) ? colsum[k] : 0;
    }
    int s = c[0] + c[1] + c[2] + c[3];
    sd[t] = s;
    __syncthreads();
    for (int off = 1; off < 256; off <<= 1) {
        int v = (t >= off) ? sd[t - off] : 0;
        __syncthreads();
        sd[t] += v;
        __syncthreads();
    }
    int pre = sd[t] - s;
#pragma unroll
    for (int j = 0; j < 4; j++) {
        int k = t * 4 + j;
        if (k < nbp) bucket_ptr[k] = pre;
        pre += c[j];
    }
    if (t == 255) bucket_ptr[nbp] = total;
}

// Radix pass 2: single-pass partition. LDS cursor = C[tile][b] + bucket_ptr[b].
__global__ __launch_bounds__(256) void k_partition(
    const int* __restrict__ src, const int* __restrict__ dst,
    const int* __restrict__ C, const int* __restrict__ bucket_ptr,
    unsigned int* __restrict__ pairs, int e, int nbp, int total) {
    __shared__ int lcur[NBMAX];
    int t = threadIdx.x;
    int tile = blockIdx.x;
    const int* row = C + (size_t)tile * nbp;
    for (int k = t; k < nbp; k += 256) lcur[k] = row[k] + bucket_ptr[k];
    __syncthreads();
    int t0 = tile * PART_TILE;
#pragma unroll 4
    for (int j = 0; j < EPT; j++) {
        int i = t0 + j * 256 + t;
        if (i < total) {
            int s, d;
            if (i < e) { s = src[i]; d = dst[i]; }
            else       { s = i - e;  d = s; }
            int b = d >> 7;
            int off = atomicAdd(&lcur[b], 1);
            pairs[off] = (unsigned int)s | ((unsigned int)(d & 127) << 17);
        }
    }
}

// Pass 3: one WG per bucket; LDS-only counts/scan/row_ptr/dinv/fine-sort.
__global__ __launch_bounds__(256) void k_build(
    const unsigned int* __restrict__ pairs, const int* __restrict__ bucket_ptr,
    int* __restrict__ row_ptr, int* __restrict__ srcs,
    float* __restrict__ dinv, int n) {
    __shared__ int cnt[NPB];
    __shared__ int scn[NPB];
    __shared__ int cur[NPB];
    int b = blockIdx.x;
    int t = threadIdx.x;
    int node0 = b << 7;
    int p0 = bucket_ptr[b], p1 = bucket_ptr[b + 1];
    if (t < NPB) cnt[t] = 0;
    __syncthreads();
    for (int i = p0 + t; i < p1; i += 256) {
        int dlow = (int)(pairs[i] >> 17) & 127;
        atomicAdd(&cnt[dlow], 1);
    }
    __syncthreads();
    if (t < NPB) scn[t] = cnt[t];
    __syncthreads();
    for (int off = 1; off < NPB; off <<= 1) {
        int v = (t < NPB && t >= off) ? scn[t - off] : 0;
        __syncthreads();
        if (t < NPB) scn[t] += v;
        __syncthreads();
    }
    if (t < NPB) {
        int incl = scn[t];
        int excl = incl - cnt[t];
        int start = p0 + excl;
        cur[t] = start;
        int node = node0 + t;
        if (node < n) {
            row_ptr[node] = start;
            dinv[node] = rsqrtf((float)cnt[t]);  // deg >= 1 (self-loop)
            if (node == n - 1) row_ptr[n] = p0 + incl;
        }
    }
    __syncthreads();
    for (int i = p0 + t; i < p1; i += 256) {
        unsigned int pr = pairs[i];
        int pos = atomicAdd(&cur[(pr >> 17) & 127], 1);
        srcs[pos] = (int)(pr & 0x1FFFFu);
    }
}

// ---------------------------------------------------------------------------
// GEMM1: G[c][r][16] = bf16( dinv[r] * (A @ W)[r][c*16..] ), A: Mx128 f32.
// Chunk-major output: chunk index == c (channel block). Split-A bf16 MFMA.
// mfma_f32_16x16x32_bf16 layouts (HW-verified, guide m89/m91):
//   A: lane holds A[m=lane&15][k=(lane>>4)*8 + j]
//   B: lane holds B[k=(lane>>4)*8 + j][n=lane&15]   (Wp is [n][k] bf16)
//   C/D: col=lane&15, row=(lane>>4)*4 + reg
// ---------------------------------------------------------------------------
__global__ __launch_bounds__(256) void k_gemm1(
    const float* __restrict__ A, const ushort_t* __restrict__ Wp,
    const float* __restrict__ dinv, ushort_t* __restrict__ G, int M) {
    int t = threadIdx.x;
    int row0 = blockIdx.x * 64;
    int wv = t >> 6;
    int lane = t & 63;
    int m = lane & 15;
    int quad = lane >> 4;

    int gr_row = row0 + wv * 16 + m;
    int gcl = gr_row < M ? gr_row : M - 1;
    const float* ap = A + (size_t)gcl * 128 + quad * 8;

    f32x4 acc[8];
#pragma unroll
    for (int c = 0; c < 8; c++) acc[c] = (f32x4){0.f, 0.f, 0.f, 0.f};

#pragma unroll
    for (int ks = 0; ks < 4; ks++) {
        int kb = ks * 32 + quad * 8;
        float xs[8];
        *(float4*)&xs[0] = *(const float4*)(ap + ks * 32);
        *(float4*)&xs[4] = *(const float4*)(ap + ks * 32 + 4);
        short8 ahi, alo;
#pragma unroll
        for (int j = 0; j < 8; j++) {
            unsigned short h = f32_to_bf16_rne(xs[j]);
            ahi[j] = (short)h;
            float hf = __uint_as_float((unsigned int)h << 16);
            alo[j] = (short)f32_to_bf16_rne(xs[j] - hf);
        }
#pragma unroll
        for (int c = 0; c < 8; c++) {
            short8 b8 = *(const short8*)(Wp + (size_t)(c * 16 + m) * 128 + kb);
            acc[c] = __builtin_amdgcn_mfma_f32_16x16x32_bf16(ahi, b8, acc[c], 0, 0, 0);
            acc[c] = __builtin_amdgcn_mfma_f32_16x16x32_bf16(alo, b8, acc[c], 0, 0, 0);
        }
    }

    int rbase = row0 + wv * 16 + quad * 4;
#pragma unroll
    for (int reg = 0; reg < 4; reg++) {
        int gr = rbase + reg;
        if (gr < M) {
            float dv = dinv[gr];
#pragma unroll
            for (int c = 0; c < 8; c++)
                G[((size_t)c * M + gr) * 16 + m] = f32_to_bf16_rne(acc[c][reg] * dv);
        }
    }
}

// ---------------------------------------------------------------------------
// GEMM2: in-place actG2[c][r][16] = bf16( dinv[r] * (act @ W2)[r][c*16..] ).
// act rows are wave-private (block = 64 rows, wave = 16 rows); in a wave all
// A-loads complete (MFMA data dep) before epilogue stores -> in-place is safe.
// Clamped tail rows may read racing data but their results are discarded.
// NOTE: actG2 deliberately NOT __restrict__ (true aliasing).
// ---------------------------------------------------------------------------
__global__ __launch_bounds__(256) void k_gemm2(
    ushort_t* actG2, const ushort_t* __restrict__ Wp,
    const float* __restrict__ dinv, int M) {
    int t = threadIdx.x;
    int row0 = blockIdx.x * 64;
    int wv = t >> 6;
    int lane = t & 63;
    int m = lane & 15;
    int quad = lane >> 4;

    int gr_row = row0 + wv * 16 + m;
    int gcl = gr_row < M ? gr_row : M - 1;

    f32x4 acc[8];
#pragma unroll
    for (int c = 0; c < 8; c++) acc[c] = (f32x4){0.f, 0.f, 0.f, 0.f};

#pragma unroll
    for (int ks = 0; ks < 4; ks++) {
        int kb = ks * 32 + quad * 8;
        // chunked act: channels kb..kb+7 live in chunk kb>>4 at offset kb&15
        short8 a8 = *(const short8*)(actG2 + ((size_t)(kb >> 4) * M + gcl) * 16 + (kb & 15));
#pragma unroll
        for (int c = 0; c < 8; c++) {
            short8 b8 = *(const short8*)(Wp + (size_t)(c * 16 + m) * 128 + kb);
            acc[c] = __builtin_amdgcn_mfma_f32_16x16x32_bf16(a8, b8, acc[c], 0, 0, 0);
        }
    }

    int rbase = row0 + wv * 16 + quad * 4;
#pragma unroll
    for (int reg = 0; reg < 4; reg++) {
        int gr = rbase + reg;
        if (gr < M) {
            float dv = dinv[gr];
#pragma unroll
            for (int c = 0; c < 8; c++)
                actG2[((size_t)c * M + gr) * 16 + m] = f32_to_bf16_rne(acc[c][reg] * dv);
        }
    }
}

// ---------------------------------------------------------------------------
// R9 chunked aggregates. gridDim.y = chunk (slow-varying -> per-pass table
// 3.2 MB L2-resident; proven at compulsory fetch floor in R8). Wave = 16
// consecutive nodes; 4 lanes per node (quad q owns channels 4q..4q+3, 8 B).
// Each quad walks its node's edge list serially (exec-masked divergence),
// unroll-4 for MLP. No cross-lane reduce; tail = 4 FMA + pack + 1 store,
// wave stores are contiguous (512 B for agg1, 16 B x 64 lanes for agg2).
// ---------------------------------------------------------------------------

#define ACC_U(u)                                     \
    do {                                             \
        unsigned int ul_ = (unsigned int)(u);        \
        unsigned int uh_ = (unsigned int)((u) >> 32);\
        a0 += __uint_as_float(ul_ << 16);            \
        a1 += __uint_as_float(ul_ & 0xffff0000u);    \
        a2 += __uint_as_float(uh_ << 16);            \
        a3 += __uint_as_float(uh_ & 0xffff0000u);    \
    } while (0)

// Aggregate 1: act[chunk][node][16] = bf16(relu(dinv*sum(G1[src]) + b1)).
__global__ __launch_bounds__(256) void k_agg1(
    const int* __restrict__ row_ptr, const int* __restrict__ srcs,
    const ushort_t* __restrict__ G, const float* __restrict__ dinv,
    const float* __restrict__ bias, ull_t* __restrict__ ActOut, int n) {
    int chunk = blockIdx.y;
    int t = threadIdx.x;
    int lane = t & 63;
    int g = lane >> 2;     // node sub-index within wave (0..15)
    int q = lane & 3;      // channel quad (4 ch = 8 B)
    int node = blockIdx.x * 64 + (t >> 6) * 16 + g;
    bool valid = node < n;
    int nc = valid ? node : n - 1;
    int beg = row_ptr[nc], end = row_ptr[nc + 1];
    const ull_t* Tq = (const ull_t*)(G + (size_t)chunk * n * 16) + q;
    float a0 = 0.f, a1 = 0.f, a2 = 0.f, a3 = 0.f;
    int e = beg;
    for (; e + 4 <= end; e += 4) {
        int s0 = srcs[e], s1 = srcs[e + 1], s2 = srcs[e + 2], s3 = srcs[e + 3];
        ull_t u0 = Tq[(size_t)s0 * 4];
        ull_t u1 = Tq[(size_t)s1 * 4];
        ull_t u2 = Tq[(size_t)s2 * 4];
        ull_t u3 = Tq[(size_t)s3 * 4];
        ACC_U(u0); ACC_U(u1); ACC_U(u2); ACC_U(u3);
    }
    for (; e < end; ++e) {
        int s = srcs[e];
        ull_t u = Tq[(size_t)s * 4];
        ACC_U(u);
    }
    if (valid) {
        float dv = dinv[node];
        const float* bp = bias + chunk * 16 + q * 4;
        a0 = fmaxf(fmaf(a0, dv, bp[0]), 0.f);
        a1 = fmaxf(fmaf(a1, dv, bp[1]), 0.f);
        a2 = fmaxf(fmaf(a2, dv, bp[2]), 0.f);
        a3 = fmaxf(fmaf(a3, dv, bp[3]), 0.f);
        unsigned int p0 = (unsigned int)f32_to_bf16_rne(a0) |
                          ((unsigned int)f32_to_bf16_rne(a1) << 16);
        unsigned int p1 = (unsigned int)f32_to_bf16_rne(a2) |
                          ((unsigned int)f32_to_bf16_rne(a3) << 16);
        ull_t uo = (ull_t)p0 | ((ull_t)p1 << 32);
        __builtin_nontemporal_store(uo, ActOut + ((size_t)chunk * n + node) * 4 + q);
    }
}

// Aggregate 2: out[node][chunk*16..] = dinv*sum(G2[src]) + b2 (f32, nt store).
__global__ __launch_bounds__(256) void k_agg2(
    const int* __restrict__ row_ptr, const int* __restrict__ srcs,
    const ushort_t* __restrict__ G, const float* __restrict__ dinv,
    const float* __restrict__ bias, float* __restrict__ Out, int n) {
    int chunk = blockIdx.y;
    int t = threadIdx.x;
    int lane = t & 63;
    int g = lane >> 2;
    int q = lane & 3;
    int node = blockIdx.x * 64 + (t >> 6) * 16 + g;
    bool valid = node < n;
    int nc = valid ? node : n - 1;
    int beg = row_ptr[nc], end = row_ptr[nc + 1];
    const ull_t* Tq = (const ull_t*)(G + (size_t)chunk * n * 16) + q;
    float a0 = 0.f, a1 = 0.f, a2 = 0.f, a3 = 0.f;
    int e = beg;
    for (; e + 4 <= end; e += 4) {
        int s0 = srcs[e], s1 = srcs[e + 1], s2 = srcs[e + 2], s3 = srcs[e + 3];
        ull_t u0 = Tq[(size_t)s0 * 4];
        ull_t u1 = Tq[(size_t)s1 * 4];
        ull_t u2 = Tq[(size_t)s2 * 4];
        ull_t u3 = Tq[(size_t)s3 * 4];
        ACC_U(u0); ACC_U(u1); ACC_U(u2); ACC_U(u3);
    }
    for (; e < end; ++e) {
        int s = srcs[e];
        ull_t u = Tq[(size_t)s * 4];
        ACC_U(u);
    }
    if (valid) {
        float dv = dinv[node];
        const float* bp = bias + chunk * 16 + q * 4;
        f32x4 o;
        o.x = fmaf(a0, dv, bp[0]);
        o.y = fmaf(a1, dv, bp[1]);
        o.z = fmaf(a2, dv, bp[2]);
        o.w = fmaf(a3, dv, bp[3]);
        __builtin_nontemporal_store(o,
            (f32x4*)(Out + (size_t)node * 128 + chunk * 16 + q * 4));
    }
}

extern "C" void kernel_launch(void* const* d_in, const int* in_sizes, int n_in,
                              void* d_out, int out_size, void* d_ws, size_t ws_size,
                              hipStream_t stream) {
    const float* x  = (const float*)d_in[0];
    const int*   ei = (const int*)d_in[1];
    const float* W1 = (const float*)d_in[2];
    const float* b1 = (const float*)d_in[3];
    const float* W2 = (const float*)d_in[4];
    const float* b2 = (const float*)d_in[5];
    float* out = (float*)d_out;

    const int C = 128;
    const int N = in_sizes[0] / C;
    const int E = in_sizes[1] / 2;
    const int* src = ei;
    const int* dst = ei + E;
    const int total = E + N;
    const int nbp = (N + NPB - 1) >> 7;                 // buckets (782)
    const int T = (total + PART_TILE - 1) / PART_TILE;  // tiles (202)

    char* ws = (char*)d_ws;
    size_t off = 0;
    auto alloc = [&](size_t bytes) -> void* {
        void* p = ws + off;
        off = (off + bytes + 511) & ~(size_t)511;
        return p;
    };
    int*   Cmat       = (int*)alloc((size_t)T * nbp * 4);       // ~632 KB
    int*   colsum     = (int*)alloc((size_t)nbp * 4);
    int*   bucket_ptr = (int*)alloc((size_t)(nbp + 1) * 4);
    int*   row_ptr    = (int*)alloc(((size_t)N + 1) * 4);
    float* dinv       = (float*)alloc((size_t)N * 4);
    int*   srcs       = (int*)alloc((size_t)total * 4);
    ushort_t* Wp1     = (ushort_t*)alloc(128 * 128 * 2);
    ushort_t* Wp2     = (ushort_t*)alloc(128 * 128 * 2);
    ushort_t* G1      = (ushort_t*)alloc((size_t)N * C * 2);
    // act/G2 (in-place, N*C*2) shares with pairs (total*4): pairs dead
    // after k_build, act written by k_agg1 afterwards.
    size_t ab = (size_t)N * C * 2, pb = (size_t)total * 4;
    void* shared = alloc(ab > pb ? ab : pb);
    ushort_t* actG2 = (ushort_t*)shared;
    unsigned int* pairs = (unsigned int*)shared;

    // ---- weight prep + radix CSR build ----
    k_wprep<<<128, 256, 0, stream>>>(W1, W2, Wp1, Wp2);
    k_hist_tiles<<<T, 256, 0, stream>>>(dst, Cmat, E, nbp, total);
    k_col_scan<<<(nbp + 255) / 256, 256, 0, stream>>>(Cmat, colsum, T, nbp);
    k_bucket_scan<<<1, 256, 0, stream>>>(colsum, bucket_ptr, nbp, total);
    k_partition<<<T, 256, 0, stream>>>(src, dst, Cmat, bucket_ptr, pairs, E, nbp, total);
    k_build<<<nbp, 256, 0, stream>>>(pairs, bucket_ptr, row_ptr, srcs, dinv, N);

    dim3 agrid((N + 63) / 64, NCHUNK);

    // ---- layer 1: G1[c][r][16] = bf16(dinv*(x@W1)); act chunked bf16 ----
    k_gemm1<<<(N + 63) / 64, 256, 0, stream>>>(x, Wp1, dinv, G1, N);
    k_agg1<<<agrid, 256, 0, stream>>>(row_ptr, srcs, G1, dinv, b1,
                                      (ull_t*)actG2, N);

    // ---- layer 2: G2 = bf16(dinv*(act@W2)) in-place chunked; out = dinv*sum+b2 ----
    k_gemm2<<<(N + 63) / 64, 256, 0, stream>>>(actG2, Wp2, dinv, N);
    k_agg2<<<agrid, 256, 0, stream>>>(row_ptr, srcs, actG2, dinv, b2, out, N);
}

// Round 4
// 658.945 us; speedup vs baseline: 1.3428x; 1.1480x over previous
//
#include <hip/hip_runtime.h>

// ---------------------------------------------------------------------------
// 2-layer GCN: out = A_norm @ relu(A_norm @ (x@W1) + b1) @ W2 (+b2)
// A_norm = D^-1/2 (A+I) D^-1/2, factored: out[d] = dinv[d]*sum_src(g[src]) + b
// with g = dinv * (x @ W).
//
// R1: two-level counting-sort CSR build. R2: bf16 G. R3/R4: MFMA GEMM.
// R5: radix CSR. R6: FAILED fusion (reverted R7). R7: unfused, 519 us.
// R8: channel-chunked gather [8][N][16] bf16, chunk = gridDim.y pass.
//     FETCH hit compulsory floor (361->202 MB) but issue-bound (308 us).
// R9: wave = 16 nodes, 4 lanes/node, serial edge walk. Issue fixed
//     (VALUBusy 19%) but FETCH 202->721 MB: 16-node waves widen the
//     resident window to ~131k nodes = 1.3 chunks -> 2+ tables live per
//     XCD L2 -> thrash. Temporal chunk separation can't survive.
// R10: SPATIAL separation: pin chunk to XCD. chunk = blockIdx.x & 7 (HW
//     round-robin workgroup->XCD), tile = blockIdx.x >> 3. Every block on
//     XCD x runs chunk x -> one 3.2 MB table per XCD L2 for the whole
//     kernel. Table compulsory 205 -> 25.6 MB; srcs ~105 MB sequential.
// Requires N <= 131072 (17-bit src in packed pairs).
// ---------------------------------------------------------------------------

#define NPB 128          // nodes per bucket (dst >> 7)
#define NBMAX 1024       // supports N <= 131072
#define EPT 64           // edges per thread in partition/hist kernels
#define PART_TILE (256 * EPT)
#define NCHUNK 8         // 128 channels / 16 per chunk

typedef unsigned short ushort_t;
typedef unsigned long long ull_t;
typedef __attribute__((ext_vector_type(8))) short short8;
typedef __attribute__((ext_vector_type(4))) float f32x4;

__device__ __forceinline__ unsigned short f32_to_bf16_rne(float x) {
    unsigned int v = __float_as_uint(x);
    unsigned int r = v + 0x7fffu + ((v >> 16) & 1u);
    return (unsigned short)(r >> 16);
}

// W (f32, [k][n]) -> Wprep (bf16, [n][k]) for both layers. 2*16384 elems.
__global__ __launch_bounds__(256) void k_wprep(
    const float* __restrict__ W1, const float* __restrict__ W2,
    ushort_t* __restrict__ Wp1, ushort_t* __restrict__ Wp2) {
    int idx = blockIdx.x * 256 + threadIdx.x;
    int which = idx >> 14;
    int e = idx & 16383;
    int n = e & 127, k = e >> 7;
    const float* W = which ? W2 : W1;
    ushort_t* Wp = which ? Wp2 : Wp1;
    Wp[n * 128 + k] = f32_to_bf16_rne(W[k * 128 + n]);
}

// Radix pass 0: per-tile bucket histogram -> C[tile][b].
__global__ __launch_bounds__(256) void k_hist_tiles(
    const int* __restrict__ dst, int* __restrict__ C,
    int e, int nbp, int total) {
    __shared__ int hist[NBMAX];
    int t = threadIdx.x;
    int tile = blockIdx.x;
    for (int k = t; k < nbp; k += 256) hist[k] = 0;
    __syncthreads();
    int t0 = tile * PART_TILE;
#pragma unroll 4
    for (int j = 0; j < EPT; j++) {
        int i = t0 + j * 256 + t;
        if (i < total) {
            int d = (i < e) ? dst[i] : (i - e);
            atomicAdd(&hist[d >> 7], 1);
        }
    }
    __syncthreads();
    int* row = C + (size_t)tile * nbp;
    for (int k = t; k < nbp; k += 256) row[k] = hist[k];
}

// Radix pass 1: column-wise exclusive scan of C over tiles; colsum[b] = total.
__global__ __launch_bounds__(256) void k_col_scan(
    int* __restrict__ C, int* __restrict__ colsum, int T, int nbp) {
    int b = blockIdx.x * 256 + threadIdx.x;
    if (b >= nbp) return;
    int running = 0;
    int t = 0;
    for (; t + 8 <= T; t += 8) {
        int v[8];
#pragma unroll
        for (int j = 0; j < 8; j++) v[j] = C[(size_t)(t + j) * nbp + b];
#pragma unroll
        for (int j = 0; j < 8; j++) {
            C[(size_t)(t + j) * nbp + b] = running;
            running += v[j];
        }
    }
    for (; t < T; t++) {
        int v = C[(size_t)t * nbp + b];
        C[(size_t)t * nbp + b] = running;
        running += v;
    }
    colsum[b] = running;
}

// Exclusive scan of colsum -> bucket_ptr. 1 WG, nbp <= 1024.
__global__ __launch_bounds__(256) void k_bucket_scan(
    const int* __restrict__ colsum, int* __restrict__ bucket_ptr,
    int nbp, int total) {
    __shared__ int sd[256];
    int t = threadIdx.x;
    int c[4];
#pragma unroll
    for (int j = 0; j < 4; j++) {
        int k = t * 4 + j;
        c[j] = (k < nbp) ? colsum[k] : 0;
    }
    int s = c[0] + c[1] + c[2] + c[3];
    sd[t] = s;
    __syncthreads();
    for (int off = 1; off < 256; off <<= 1) {
        int v = (t >= off) ? sd[t - off] : 0;
        __syncthreads();
        sd[t] += v;
        __syncthreads();
    }
    int pre = sd[t] - s;
#pragma unroll
    for (int j = 0; j < 4; j++) {
        int k = t * 4 + j;
        if (k < nbp) bucket_ptr[k] = pre;
        pre += c[j];
    }
    if (t == 255) bucket_ptr[nbp] = total;
}

// Radix pass 2: single-pass partition. LDS cursor = C[tile][b] + bucket_ptr[b].
__global__ __launch_bounds__(256) void k_partition(
    const int* __restrict__ src, const int* __restrict__ dst,
    const int* __restrict__ C, const int* __restrict__ bucket_ptr,
    unsigned int* __restrict__ pairs, int e, int nbp, int total) {
    __shared__ int lcur[NBMAX];
    int t = threadIdx.x;
    int tile = blockIdx.x;
    const int* row = C + (size_t)tile * nbp;
    for (int k = t; k < nbp; k += 256) lcur[k] = row[k] + bucket_ptr[k];
    __syncthreads();
    int t0 = tile * PART_TILE;
#pragma unroll 4
    for (int j = 0; j < EPT; j++) {
        int i = t0 + j * 256 + t;
        if (i < total) {
            int s, d;
            if (i < e) { s = src[i]; d = dst[i]; }
            else       { s = i - e;  d = s; }
            int b = d >> 7;
            int off = atomicAdd(&lcur[b], 1);
            pairs[off] = (unsigned int)s | ((unsigned int)(d & 127) << 17);
        }
    }
}

// Pass 3: one WG per bucket; LDS-only counts/scan/row_ptr/dinv/fine-sort.
__global__ __launch_bounds__(256) void k_build(
    const unsigned int* __restrict__ pairs, const int* __restrict__ bucket_ptr,
    int* __restrict__ row_ptr, int* __restrict__ srcs,
    float* __restrict__ dinv, int n) {
    __shared__ int cnt[NPB];
    __shared__ int scn[NPB];
    __shared__ int cur[NPB];
    int b = blockIdx.x;
    int t = threadIdx.x;
    int node0 = b << 7;
    int p0 = bucket_ptr[b], p1 = bucket_ptr[b + 1];
    if (t < NPB) cnt[t] = 0;
    __syncthreads();
    for (int i = p0 + t; i < p1; i += 256) {
        int dlow = (int)(pairs[i] >> 17) & 127;
        atomicAdd(&cnt[dlow], 1);
    }
    __syncthreads();
    if (t < NPB) scn[t] = cnt[t];
    __syncthreads();
    for (int off = 1; off < NPB; off <<= 1) {
        int v = (t < NPB && t >= off) ? scn[t - off] : 0;
        __syncthreads();
        if (t < NPB) scn[t] += v;
        __syncthreads();
    }
    if (t < NPB) {
        int incl = scn[t];
        int excl = incl - cnt[t];
        int start = p0 + excl;
        cur[t] = start;
        int node = node0 + t;
        if (node < n) {
            row_ptr[node] = start;
            dinv[node] = rsqrtf((float)cnt[t]);  // deg >= 1 (self-loop)
            if (node == n - 1) row_ptr[n] = p0 + incl;
        }
    }
    __syncthreads();
    for (int i = p0 + t; i < p1; i += 256) {
        unsigned int pr = pairs[i];
        int pos = atomicAdd(&cur[(pr >> 17) & 127], 1);
        srcs[pos] = (int)(pr & 0x1FFFFu);
    }
}

// ---------------------------------------------------------------------------
// GEMM1: G[c][r][16] = bf16( dinv[r] * (A @ W)[r][c*16..] ), A: Mx128 f32.
// Chunk-major output: chunk index == c (channel block). Split-A bf16 MFMA.
// mfma_f32_16x16x32_bf16 layouts (HW-verified, guide m89/m91):
//   A: lane holds A[m=lane&15][k=(lane>>4)*8 + j]
//   B: lane holds B[k=(lane>>4)*8 + j][n=lane&15]   (Wp is [n][k] bf16)
//   C/D: col=lane&15, row=(lane>>4)*4 + reg
// ---------------------------------------------------------------------------
__global__ __launch_bounds__(256) void k_gemm1(
    const float* __restrict__ A, const ushort_t* __restrict__ Wp,
    const float* __restrict__ dinv, ushort_t* __restrict__ G, int M) {
    int t = threadIdx.x;
    int row0 = blockIdx.x * 64;
    int wv = t >> 6;
    int lane = t & 63;
    int m = lane & 15;
    int quad = lane >> 4;

    int gr_row = row0 + wv * 16 + m;
    int gcl = gr_row < M ? gr_row : M - 1;
    const float* ap = A + (size_t)gcl * 128 + quad * 8;

    f32x4 acc[8];
#pragma unroll
    for (int c = 0; c < 8; c++) acc[c] = (f32x4){0.f, 0.f, 0.f, 0.f};

#pragma unroll
    for (int ks = 0; ks < 4; ks++) {
        int kb = ks * 32 + quad * 8;
        float xs[8];
        *(float4*)&xs[0] = *(const float4*)(ap + ks * 32);
        *(float4*)&xs[4] = *(const float4*)(ap + ks * 32 + 4);
        short8 ahi, alo;
#pragma unroll
        for (int j = 0; j < 8; j++) {
            unsigned short h = f32_to_bf16_rne(xs[j]);
            ahi[j] = (short)h;
            float hf = __uint_as_float((unsigned int)h << 16);
            alo[j] = (short)f32_to_bf16_rne(xs[j] - hf);
        }
#pragma unroll
        for (int c = 0; c < 8; c++) {
            short8 b8 = *(const short8*)(Wp + (size_t)(c * 16 + m) * 128 + kb);
            acc[c] = __builtin_amdgcn_mfma_f32_16x16x32_bf16(ahi, b8, acc[c], 0, 0, 0);
            acc[c] = __builtin_amdgcn_mfma_f32_16x16x32_bf16(alo, b8, acc[c], 0, 0, 0);
        }
    }

    int rbase = row0 + wv * 16 + quad * 4;
#pragma unroll
    for (int reg = 0; reg < 4; reg++) {
        int gr = rbase + reg;
        if (gr < M) {
            float dv = dinv[gr];
#pragma unroll
            for (int c = 0; c < 8; c++)
                G[((size_t)c * M + gr) * 16 + m] = f32_to_bf16_rne(acc[c][reg] * dv);
        }
    }
}

// ---------------------------------------------------------------------------
// GEMM2: in-place actG2[c][r][16] = bf16( dinv[r] * (act @ W2)[r][c*16..] ).
// act rows are wave-private (block = 64 rows, wave = 16 rows); in a wave all
// A-loads complete (MFMA data dep) before epilogue stores -> in-place is safe.
// Clamped tail rows may read racing data but their results are discarded.
// NOTE: actG2 deliberately NOT __restrict__ (true aliasing).
// ---------------------------------------------------------------------------
__global__ __launch_bounds__(256) void k_gemm2(
    ushort_t* actG2, const ushort_t* __restrict__ Wp,
    const float* __restrict__ dinv, int M) {
    int t = threadIdx.x;
    int row0 = blockIdx.x * 64;
    int wv = t >> 6;
    int lane = t & 63;
    int m = lane & 15;
    int quad = lane >> 4;

    int gr_row = row0 + wv * 16 + m;
    int gcl = gr_row < M ? gr_row : M - 1;

    f32x4 acc[8];
#pragma unroll
    for (int c = 0; c < 8; c++) acc[c] = (f32x4){0.f, 0.f, 0.f, 0.f};

#pragma unroll
    for (int ks = 0; ks < 4; ks++) {
        int kb = ks * 32 + quad * 8;
        // chunked act: channels kb..kb+7 live in chunk kb>>4 at offset kb&15
        short8 a8 = *(const short8*)(actG2 + ((size_t)(kb >> 4) * M + gcl) * 16 + (kb & 15));
#pragma unroll
        for (int c = 0; c < 8; c++) {
            short8 b8 = *(const short8*)(Wp + (size_t)(c * 16 + m) * 128 + kb);
            acc[c] = __builtin_amdgcn_mfma_f32_16x16x32_bf16(a8, b8, acc[c], 0, 0, 0);
        }
    }

    int rbase = row0 + wv * 16 + quad * 4;
#pragma unroll
    for (int reg = 0; reg < 4; reg++) {
        int gr = rbase + reg;
        if (gr < M) {
            float dv = dinv[gr];
#pragma unroll
            for (int c = 0; c < 8; c++)
                actG2[((size_t)c * M + gr) * 16 + m] = f32_to_bf16_rne(acc[c][reg] * dv);
        }
    }
}

// ---------------------------------------------------------------------------
// R10 XCD-pinned chunked aggregates. chunk = blockIdx.x & 7: HW round-robin
// workgroup->XCD dispatch puts all chunk-c blocks on XCD c, so each XCD's
// L2 holds exactly ONE 3.2 MB chunk table for the whole kernel (no reliance
// on dispatch timing). tile = blockIdx.x >> 3 selects the 64-node group.
// Wave = 16 consecutive nodes; 4 lanes per node (quad q owns channels
// 4q..4q+3, 8 B). Serial exec-masked edge walk, unroll-4, no cross-lane
// reduce (R9 structure: VALUBusy 19% proved issue side fine).
// ---------------------------------------------------------------------------

#define ACC_U(u)                                     \
    do {                                             \
        unsigned int ul_ = (unsigned int)(u);        \
        unsigned int uh_ = (unsigned int)((u) >> 32);\
        a0 += __uint_as_float(ul_ << 16);            \
        a1 += __uint_as_float(ul_ & 0xffff0000u);    \
        a2 += __uint_as_float(uh_ << 16);            \
        a3 += __uint_as_float(uh_ & 0xffff0000u);    \
    } while (0)

// Aggregate 1: act[chunk][node][16] = bf16(relu(dinv*sum(G1[src]) + b1)).
__global__ __launch_bounds__(256) void k_agg1(
    const int* __restrict__ row_ptr, const int* __restrict__ srcs,
    const ushort_t* __restrict__ G, const float* __restrict__ dinv,
    const float* __restrict__ bias, ull_t* __restrict__ ActOut, int n) {
    int chunk = blockIdx.x & 7;          // XCD-pinned chunk
    int tile = blockIdx.x >> 3;
    int t = threadIdx.x;
    int lane = t & 63;
    int g = lane >> 2;     // node sub-index within wave (0..15)
    int q = lane & 3;      // channel quad (4 ch = 8 B)
    int node = tile * 64 + (t >> 6) * 16 + g;
    bool valid = node < n;
    int nc = valid ? node : n - 1;
    int beg = row_ptr[nc], end = row_ptr[nc + 1];
    const ull_t* Tq = (const ull_t*)(G + (size_t)chunk * n * 16) + q;
    float a0 = 0.f, a1 = 0.f, a2 = 0.f, a3 = 0.f;
    int e = beg;
    for (; e + 4 <= end; e += 4) {
        int s0 = srcs[e], s1 = srcs[e + 1], s2 = srcs[e + 2], s3 = srcs[e + 3];
        ull_t u0 = Tq[(size_t)s0 * 4];
        ull_t u1 = Tq[(size_t)s1 * 4];
        ull_t u2 = Tq[(size_t)s2 * 4];
        ull_t u3 = Tq[(size_t)s3 * 4];
        ACC_U(u0); ACC_U(u1); ACC_U(u2); ACC_U(u3);
    }
    for (; e < end; ++e) {
        int s = srcs[e];
        ull_t u = Tq[(size_t)s * 4];
        ACC_U(u);
    }
    if (valid) {
        float dv = dinv[node];
        const float* bp = bias + chunk * 16 + q * 4;
        a0 = fmaxf(fmaf(a0, dv, bp[0]), 0.f);
        a1 = fmaxf(fmaf(a1, dv, bp[1]), 0.f);
        a2 = fmaxf(fmaf(a2, dv, bp[2]), 0.f);
        a3 = fmaxf(fmaf(a3, dv, bp[3]), 0.f);
        unsigned int p0 = (unsigned int)f32_to_bf16_rne(a0) |
                          ((unsigned int)f32_to_bf16_rne(a1) << 16);
        unsigned int p1 = (unsigned int)f32_to_bf16_rne(a2) |
                          ((unsigned int)f32_to_bf16_rne(a3) << 16);
        ull_t uo = (ull_t)p0 | ((ull_t)p1 << 32);
        __builtin_nontemporal_store(uo, ActOut + ((size_t)chunk * n + node) * 4 + q);
    }
}

// Aggregate 2: out[node][chunk*16..] = dinv*sum(G2[src]) + b2 (f32, nt store).
__global__ __launch_bounds__(256) void k_agg2(
    const int* __restrict__ row_ptr, const int* __restrict__ srcs,
    const ushort_t* __restrict__ G, const float* __restrict__ dinv,
    const float* __restrict__ bias, float* __restrict__ Out, int n) {
    int chunk = blockIdx.x & 7;          // XCD-pinned chunk
    int tile = blockIdx.x >> 3;
    int t = threadIdx.x;
    int lane = t & 63;
    int g = lane >> 2;
    int q = lane & 3;
    int node = tile * 64 + (t >> 6) * 16 + g;
    bool valid = node < n;
    int nc = valid ? node : n - 1;
    int beg = row_ptr[nc], end = row_ptr[nc + 1];
    const ull_t* Tq = (const ull_t*)(G + (size_t)chunk * n * 16) + q;
    float a0 = 0.f, a1 = 0.f, a2 = 0.f, a3 = 0.f;
    int e = beg;
    for (; e + 4 <= end; e += 4) {
        int s0 = srcs[e], s1 = srcs[e + 1], s2 = srcs[e + 2], s3 = srcs[e + 3];
        ull_t u0 = Tq[(size_t)s0 * 4];
        ull_t u1 = Tq[(size_t)s1 * 4];
        ull_t u2 = Tq[(size_t)s2 * 4];
        ull_t u3 = Tq[(size_t)s3 * 4];
        ACC_U(u0); ACC_U(u1); ACC_U(u2); ACC_U(u3);
    }
    for (; e < end; ++e) {
        int s = srcs[e];
        ull_t u = Tq[(size_t)s * 4];
        ACC_U(u);
    }
    if (valid) {
        float dv = dinv[node];
        const float* bp = bias + chunk * 16 + q * 4;
        f32x4 o;
        o.x = fmaf(a0, dv, bp[0]);
        o.y = fmaf(a1, dv, bp[1]);
        o.z = fmaf(a2, dv, bp[2]);
        o.w = fmaf(a3, dv, bp[3]);
        __builtin_nontemporal_store(o,
            (f32x4*)(Out + (size_t)node * 128 + chunk * 16 + q * 4));
    }
}

extern "C" void kernel_launch(void* const* d_in, const int* in_sizes, int n_in,
                              void* d_out, int out_size, void* d_ws, size_t ws_size,
                              hipStream_t stream) {
    const float* x  = (const float*)d_in[0];
    const int*   ei = (const int*)d_in[1];
    const float* W1 = (const float*)d_in[2];
    const float* b1 = (const float*)d_in[3];
    const float* W2 = (const float*)d_in[4];
    const float* b2 = (const float*)d_in[5];
    float* out = (float*)d_out;

    const int C = 128;
    const int N = in_sizes[0] / C;
    const int E = in_sizes[1] / 2;
    const int* src = ei;
    const int* dst = ei + E;
    const int total = E + N;
    const int nbp = (N + NPB - 1) >> 7;                 // buckets (782)
    const int T = (total + PART_TILE - 1) / PART_TILE;  // tiles (202)

    char* ws = (char*)d_ws;
    size_t off = 0;
    auto alloc = [&](size_t bytes) -> void* {
        void* p = ws + off;
        off = (off + bytes + 511) & ~(size_t)511;
        return p;
    };
    int*   Cmat       = (int*)alloc((size_t)T * nbp * 4);       // ~632 KB
    int*   colsum     = (int*)alloc((size_t)nbp * 4);
    int*   bucket_ptr = (int*)alloc((size_t)(nbp + 1) * 4);
    int*   row_ptr    = (int*)alloc(((size_t)N + 1) * 4);
    float* dinv       = (float*)alloc((size_t)N * 4);
    int*   srcs       = (int*)alloc((size_t)total * 4);
    ushort_t* Wp1     = (ushort_t*)alloc(128 * 128 * 2);
    ushort_t* Wp2     = (ushort_t*)alloc(128 * 128 * 2);
    ushort_t* G1      = (ushort_t*)alloc((size_t)N * C * 2);
    // act/G2 (in-place, N*C*2) shares with pairs (total*4): pairs dead
    // after k_build, act written by k_agg1 afterwards.
    size_t ab = (size_t)N * C * 2, pb = (size_t)total * 4;
    void* shared = alloc(ab > pb ? ab : pb);
    ushort_t* actG2 = (ushort_t*)shared;
    unsigned int* pairs = (unsigned int*)shared;

    // ---- weight prep + radix CSR build ----
    k_wprep<<<128, 256, 0, stream>>>(W1, W2, Wp1, Wp2);
    k_hist_tiles<<<T, 256, 0, stream>>>(dst, Cmat, E, nbp, total);
    k_col_scan<<<(nbp + 255) / 256, 256, 0, stream>>>(Cmat, colsum, T, nbp);
    k_bucket_scan<<<1, 256, 0, stream>>>(colsum, bucket_ptr, nbp, total);
    k_partition<<<T, 256, 0, stream>>>(src, dst, Cmat, bucket_ptr, pairs, E, nbp, total);
    k_build<<<nbp, 256, 0, stream>>>(pairs, bucket_ptr, row_ptr, srcs, dinv, N);

    // XCD-pinned agg grid: 8 chunks interleaved in blockIdx.x (chunk = bx&7)
    const int NTILE = (N + 63) / 64;      // 64-node tiles per chunk
    dim3 agrid(NTILE * NCHUNK);

    // ---- layer 1: G1[c][r][16] = bf16(dinv*(x@W1)); act chunked bf16 ----
    k_gemm1<<<(N + 63) / 64, 256, 0, stream>>>(x, Wp1, dinv, G1, N);
    k_agg1<<<agrid, 256, 0, stream>>>(row_ptr, srcs, G1, dinv, b1,
                                      (ull_t*)actG2, N);

    // ---- layer 2: G2 = bf16(dinv*(act@W2)) in-place chunked; out = dinv*sum+b2 ----
    k_gemm2<<<(N + 63) / 64, 256, 0, stream>>>(actG2, Wp2, dinv, N);
    k_agg2<<<agrid, 256, 0, stream>>>(row_ptr, srcs, actG2, dinv, b2, out, N);
}

// Round 6
// 508.927 us; speedup vs baseline: 1.7386x; 1.2948x over previous
//
#include <hip/hip_runtime.h>

// ---------------------------------------------------------------------------
// 2-layer GCN: out = A_norm @ relu(A_norm @ (x@W1) + b1) @ W2 (+b2)
// A_norm = D^-1/2 (A+I) D^-1/2, factored: out[d] = dinv[d]*sum_src(g[src]) + b
// with g = dinv * (x @ W).
//
// R1: counting-sort CSR. R2: bf16 G. R3/R4: MFMA GEMM. R5: radix CSR.
// R6: FAILED fusion. R7: unfused baseline, 519 us (agg 110+110, rest ~300).
// R8 (16ch x 8pass temporal): FETCH floor 202 MB but issue-bound, 308 us.
// R9 (16-node waves): issue fixed, but resident window = 1.3 chunks ->
//     L2 thrash, FETCH 721 MB. R10 (XCD-pinned): FETCH 327 MB, dur 184 --
//     L2 LINE-SLOT bound: 32 B/edge still touches a full 128 B line;
//     8 passes = 26.4M touches @ ~144 G/s = the 184 us.
// R11: 64-channel chunks [2][N][64] bf16 = 128 B/node/pass = ONE FULL LINE
//     per edge (100% line use, 6.6M touches = R7's minimum) x 2 passes.
//     Working set 12.8 MB (vs R7's 25.6) -> higher L2 hit rate; chunks are
//     sequential grid halves so one table is live at a time. Wave = 4 nodes
//     x 16 lanes (8 B each). wprep folded into bucket_scan.
//     (R11b: resubmit after container infra failure.)
// Requires N <= 131072 (17-bit src in packed pairs).
// ---------------------------------------------------------------------------

#define NPB 128          // nodes per bucket (dst >> 7)
#define NBMAX 1024       // supports N <= 131072
#define EPT 64           // edges per thread in partition/hist kernels
#define PART_TILE (256 * EPT)

typedef unsigned short ushort_t;
typedef unsigned long long ull_t;
typedef __attribute__((ext_vector_type(8))) short short8;
typedef __attribute__((ext_vector_type(4))) float f32x4;

__device__ __forceinline__ unsigned short f32_to_bf16_rne(float x) {
    unsigned int v = __float_as_uint(x);
    unsigned int r = v + 0x7fffu + ((v >> 16) & 1u);
    return (unsigned short)(r >> 16);
}

// Radix pass 0: per-tile bucket histogram -> C[tile][b].
__global__ __launch_bounds__(256) void k_hist_tiles(
    const int* __restrict__ dst, int* __restrict__ C,
    int e, int nbp, int total) {
    __shared__ int hist[NBMAX];
    int t = threadIdx.x;
    int tile = blockIdx.x;
    for (int k = t; k < nbp; k += 256) hist[k] = 0;
    __syncthreads();
    int t0 = tile * PART_TILE;
#pragma unroll 4
    for (int j = 0; j < EPT; j++) {
        int i = t0 + j * 256 + t;
        if (i < total) {
            int d = (i < e) ? dst[i] : (i - e);
            atomicAdd(&hist[d >> 7], 1);
        }
    }
    __syncthreads();
    int* row = C + (size_t)tile * nbp;
    for (int k = t; k < nbp; k += 256) row[k] = hist[k];
}

// Radix pass 1: column-wise exclusive scan of C over tiles; colsum[b] = total.
__global__ __launch_bounds__(256) void k_col_scan(
    int* __restrict__ C, int* __restrict__ colsum, int T, int nbp) {
    int b = blockIdx.x * 256 + threadIdx.x;
    if (b >= nbp) return;
    int running = 0;
    int t = 0;
    for (; t + 8 <= T; t += 8) {
        int v[8];
#pragma unroll
        for (int j = 0; j < 8; j++) v[j] = C[(size_t)(t + j) * nbp + b];
#pragma unroll
        for (int j = 0; j < 8; j++) {
            C[(size_t)(t + j) * nbp + b] = running;
            running += v[j];
        }
    }
    for (; t < T; t++) {
        int v = C[(size_t)t * nbp + b];
        C[(size_t)t * nbp + b] = running;
        running += v;
    }
    colsum[b] = running;
}

// Exclusive scan of colsum -> bucket_ptr (block 0); blocks 1..128 do weight
// prep W (f32, [k][n]) -> Wp (bf16, [n][k]) for both layers (folded k_wprep).
__global__ __launch_bounds__(256) void k_bucket_scan(
    const int* __restrict__ colsum, int* __restrict__ bucket_ptr,
    int nbp, int total,
    const float* __restrict__ W1, const float* __restrict__ W2,
    ushort_t* __restrict__ Wp1, ushort_t* __restrict__ Wp2) {
    if (blockIdx.x > 0) {
        int idx = (blockIdx.x - 1) * 256 + threadIdx.x;
        int which = idx >> 14;
        int e = idx & 16383;
        int n = e & 127, k = e >> 7;
        const float* W = which ? W2 : W1;
        ushort_t* Wp = which ? Wp2 : Wp1;
        Wp[n * 128 + k] = f32_to_bf16_rne(W[k * 128 + n]);
        return;
    }
    __shared__ int sd[256];
    int t = threadIdx.x;
    int c[4];
#pragma unroll
    for (int j = 0; j < 4; j++) {
        int k = t * 4 + j;
        c[j] = (k < nbp) ? colsum[k] : 0;
    }
    int s = c[0] + c[1] + c[2] + c[3];
    sd[t] = s;
    __syncthreads();
    for (int off = 1; off < 256; off <<= 1) {
        int v = (t >= off) ? sd[t - off] : 0;
        __syncthreads();
        sd[t] += v;
        __syncthreads();
    }
    int pre = sd[t] - s;
#pragma unroll
    for (int j = 0; j < 4; j++) {
        int k = t * 4 + j;
        if (k < nbp) bucket_ptr[k] = pre;
        pre += c[j];
    }
    if (t == 255) bucket_ptr[nbp] = total;
}

// Radix pass 2: single-pass partition. LDS cursor = C[tile][b] + bucket_ptr[b].
__global__ __launch_bounds__(256) void k_partition(
    const int* __restrict__ src, const int* __restrict__ dst,
    const int* __restrict__ C, const int* __restrict__ bucket_ptr,
    unsigned int* __restrict__ pairs, int e, int nbp, int total) {
    __shared__ int lcur[NBMAX];
    int t = threadIdx.x;
    int tile = blockIdx.x;
    const int* row = C + (size_t)tile * nbp;
    for (int k = t; k < nbp; k += 256) lcur[k] = row[k] + bucket_ptr[k];
    __syncthreads();
    int t0 = tile * PART_TILE;
#pragma unroll 4
    for (int j = 0; j < EPT; j++) {
        int i = t0 + j * 256 + t;
        if (i < total) {
            int s, d;
            if (i < e) { s = src[i]; d = dst[i]; }
            else       { s = i - e;  d = s; }
            int b = d >> 7;
            int off = atomicAdd(&lcur[b], 1);
            pairs[off] = (unsigned int)s | ((unsigned int)(d & 127) << 17);
        }
    }
}

// Pass 3: one WG per bucket; LDS-only counts/scan/row_ptr/dinv/fine-sort.
__global__ __launch_bounds__(256) void k_build(
    const unsigned int* __restrict__ pairs, const int* __restrict__ bucket_ptr,
    int* __restrict__ row_ptr, int* __restrict__ srcs,
    float* __restrict__ dinv, int n) {
    __shared__ int cnt[NPB];
    __shared__ int scn[NPB];
    __shared__ int cur[NPB];
    int b = blockIdx.x;
    int t = threadIdx.x;
    int node0 = b << 7;
    int p0 = bucket_ptr[b], p1 = bucket_ptr[b + 1];
    if (t < NPB) cnt[t] = 0;
    __syncthreads();
    for (int i = p0 + t; i < p1; i += 256) {
        int dlow = (int)(pairs[i] >> 17) & 127;
        atomicAdd(&cnt[dlow], 1);
    }
    __syncthreads();
    if (t < NPB) scn[t] = cnt[t];
    __syncthreads();
    for (int off = 1; off < NPB; off <<= 1) {
        int v = (t < NPB && t >= off) ? scn[t - off] : 0;
        __syncthreads();
        if (t < NPB) scn[t] += v;
        __syncthreads();
    }
    if (t < NPB) {
        int incl = scn[t];
        int excl = incl - cnt[t];
        int start = p0 + excl;
        cur[t] = start;
        int node = node0 + t;
        if (node < n) {
            row_ptr[node] = start;
            dinv[node] = rsqrtf((float)cnt[t]);  // deg >= 1 (self-loop)
            if (node == n - 1) row_ptr[n] = p0 + incl;
        }
    }
    __syncthreads();
    for (int i = p0 + t; i < p1; i += 256) {
        unsigned int pr = pairs[i];
        int pos = atomicAdd(&cur[(pr >> 17) & 127], 1);
        srcs[pos] = (int)(pr & 0x1FFFFu);
    }
}

// ---------------------------------------------------------------------------
// GEMM1: G[ch][r][64] = bf16( dinv[r] * (A @ W)[r][ch*64..] ), A: Mx128 f32.
// 64-channel-chunk-major output ([2][M][64] bf16). Split-A bf16 MFMA.
// mfma_f32_16x16x32_bf16 layouts (HW-verified, guide m89/m91):
//   A: lane holds A[m=lane&15][k=(lane>>4)*8 + j]
//   B: lane holds B[k=(lane>>4)*8 + j][n=lane&15]   (Wp is [n][k] bf16)
//   C/D: col=lane&15, row=(lane>>4)*4 + reg
// Channel c*16+m lives in chunk c>>2 at offset (c&3)*16 + m.
// ---------------------------------------------------------------------------
__global__ __launch_bounds__(256) void k_gemm1(
    const float* __restrict__ A, const ushort_t* __restrict__ Wp,
    const float* __restrict__ dinv, ushort_t* __restrict__ G, int M) {
    int t = threadIdx.x;
    int row0 = blockIdx.x * 64;
    int wv = t >> 6;
    int lane = t & 63;
    int m = lane & 15;
    int quad = lane >> 4;

    int gr_row = row0 + wv * 16 + m;
    int gcl = gr_row < M ? gr_row : M - 1;
    const float* ap = A + (size_t)gcl * 128 + quad * 8;

    f32x4 acc[8];
#pragma unroll
    for (int c = 0; c < 8; c++) acc[c] = (f32x4){0.f, 0.f, 0.f, 0.f};

#pragma unroll
    for (int ks = 0; ks < 4; ks++) {
        int kb = ks * 32 + quad * 8;
        float xs[8];
        *(float4*)&xs[0] = *(const float4*)(ap + ks * 32);
        *(float4*)&xs[4] = *(const float4*)(ap + ks * 32 + 4);
        short8 ahi, alo;
#pragma unroll
        for (int j = 0; j < 8; j++) {
            unsigned short h = f32_to_bf16_rne(xs[j]);
            ahi[j] = (short)h;
            float hf = __uint_as_float((unsigned int)h << 16);
            alo[j] = (short)f32_to_bf16_rne(xs[j] - hf);
        }
#pragma unroll
        for (int c = 0; c < 8; c++) {
            short8 b8 = *(const short8*)(Wp + (size_t)(c * 16 + m) * 128 + kb);
            acc[c] = __builtin_amdgcn_mfma_f32_16x16x32_bf16(ahi, b8, acc[c], 0, 0, 0);
            acc[c] = __builtin_amdgcn_mfma_f32_16x16x32_bf16(alo, b8, acc[c], 0, 0, 0);
        }
    }

    int rbase = row0 + wv * 16 + quad * 4;
#pragma unroll
    for (int reg = 0; reg < 4; reg++) {
        int gr = rbase + reg;
        if (gr < M) {
            float dv = dinv[gr];
#pragma unroll
            for (int c = 0; c < 8; c++)
                G[((size_t)(c >> 2) * M + gr) * 64 + (c & 3) * 16 + m] =
                    f32_to_bf16_rne(acc[c][reg] * dv);
        }
    }
}

// ---------------------------------------------------------------------------
// GEMM2: in-place actG2[ch][r][64] = bf16( dinv[r] * (act @ W2)[r][..] ).
// act rows are wave-private (block = 64 rows, wave = 16 rows); in a wave all
// A-loads complete (MFMA data dep) before epilogue stores -> in-place is safe.
// Clamped tail rows may read racing data but their results are discarded.
// NOTE: actG2 deliberately NOT __restrict__ (true aliasing).
// ---------------------------------------------------------------------------
__global__ __launch_bounds__(256) void k_gemm2(
    ushort_t* actG2, const ushort_t* __restrict__ Wp,
    const float* __restrict__ dinv, int M) {
    int t = threadIdx.x;
    int row0 = blockIdx.x * 64;
    int wv = t >> 6;
    int lane = t & 63;
    int m = lane & 15;
    int quad = lane >> 4;

    int gr_row = row0 + wv * 16 + m;
    int gcl = gr_row < M ? gr_row : M - 1;

    f32x4 acc[8];
#pragma unroll
    for (int c = 0; c < 8; c++) acc[c] = (f32x4){0.f, 0.f, 0.f, 0.f};

#pragma unroll
    for (int ks = 0; ks < 4; ks++) {
        int kb = ks * 32 + quad * 8;
        // chunked act: channels kb..kb+7 live in chunk kb>>6 at offset kb&63
        short8 a8 = *(const short8*)(actG2 + ((size_t)(kb >> 6) * M + gcl) * 64 + (kb & 63));
#pragma unroll
        for (int c = 0; c < 8; c++) {
            short8 b8 = *(const short8*)(Wp + (size_t)(c * 16 + m) * 128 + kb);
            acc[c] = __builtin_amdgcn_mfma_f32_16x16x32_bf16(a8, b8, acc[c], 0, 0, 0);
        }
    }

    int rbase = row0 + wv * 16 + quad * 4;
#pragma unroll
    for (int reg = 0; reg < 4; reg++) {
        int gr = rbase + reg;
        if (gr < M) {
            float dv = dinv[gr];
#pragma unroll
            for (int c = 0; c < 8; c++)
                actG2[((size_t)(c >> 2) * M + gr) * 64 + (c & 3) * 16 + m] =
                    f32_to_bf16_rne(acc[c][reg] * dv);
        }
    }
}

// ---------------------------------------------------------------------------
// R11 aggregates: 2 passes of 64 channels. Table per pass = N*128 B =
// 12.8 MB; each edge touches exactly ONE fully-used 128 B line (6.6M total
// line-touches = structural minimum). chunk = (bx >= half) sequential
// halves -> one table live at a time. Wave = 4 nodes x 16 lanes (8 B/lane).
// Serial exec-masked edge walk per 16-lane group, unroll-4 MLP.
// ---------------------------------------------------------------------------

#define ACC_U(u)                                     \
    do {                                             \
        unsigned int ul_ = (unsigned int)(u);        \
        unsigned int uh_ = (unsigned int)((u) >> 32);\
        a0 += __uint_as_float(ul_ << 16);            \
        a1 += __uint_as_float(ul_ & 0xffff0000u);    \
        a2 += __uint_as_float(uh_ << 16);            \
        a3 += __uint_as_float(uh_ & 0xffff0000u);    \
    } while (0)

// Aggregate 1: act[chunk][node][64] = bf16(relu(dinv*sum(G1[src]) + b1)).
__global__ __launch_bounds__(256) void k_agg1(
    const int* __restrict__ row_ptr, const int* __restrict__ srcs,
    const ushort_t* __restrict__ G, const float* __restrict__ dinv,
    const float* __restrict__ bias, ull_t* __restrict__ ActOut,
    int n, int half) {
    int bx = blockIdx.x;
    int chunk = bx >= half ? 1 : 0;
    int tile = bx - chunk * half;
    int t = threadIdx.x;
    int lane = t & 63;
    int g = lane >> 4;     // node sub-index within wave (0..3)
    int q = lane & 15;     // 8 B quad within 64 channels
    int node = tile * 16 + (t >> 6) * 4 + g;
    bool valid = node < n;
    int nc = valid ? node : n - 1;
    int beg = row_ptr[nc], end = row_ptr[nc + 1];
    const ull_t* Tq = (const ull_t*)G + (size_t)chunk * n * 16 + q;
    float a0 = 0.f, a1 = 0.f, a2 = 0.f, a3 = 0.f;
    int e = beg;
    for (; e + 4 <= end; e += 4) {
        int s0 = srcs[e], s1 = srcs[e + 1], s2 = srcs[e + 2], s3 = srcs[e + 3];
        ull_t u0 = Tq[(size_t)s0 * 16];
        ull_t u1 = Tq[(size_t)s1 * 16];
        ull_t u2 = Tq[(size_t)s2 * 16];
        ull_t u3 = Tq[(size_t)s3 * 16];
        ACC_U(u0); ACC_U(u1); ACC_U(u2); ACC_U(u3);
    }
    for (; e < end; ++e) {
        int s = srcs[e];
        ull_t u = Tq[(size_t)s * 16];
        ACC_U(u);
    }
    if (valid) {
        float dv = dinv[node];
        const float* bp = bias + chunk * 64 + q * 4;
        a0 = fmaxf(fmaf(a0, dv, bp[0]), 0.f);
        a1 = fmaxf(fmaf(a1, dv, bp[1]), 0.f);
        a2 = fmaxf(fmaf(a2, dv, bp[2]), 0.f);
        a3 = fmaxf(fmaf(a3, dv, bp[3]), 0.f);
        unsigned int p0 = (unsigned int)f32_to_bf16_rne(a0) |
                          ((unsigned int)f32_to_bf16_rne(a1) << 16);
        unsigned int p1 = (unsigned int)f32_to_bf16_rne(a2) |
                          ((unsigned int)f32_to_bf16_rne(a3) << 16);
        ull_t uo = (ull_t)p0 | ((ull_t)p1 << 32);
        __builtin_nontemporal_store(uo, ActOut + ((size_t)chunk * n + node) * 16 + q);
    }
}

// Aggregate 2: out[node][chunk*64..] = dinv*sum(G2[src]) + b2 (f32, nt store).
__global__ __launch_bounds__(256) void k_agg2(
    const int* __restrict__ row_ptr, const int* __restrict__ srcs,
    const ushort_t* __restrict__ G, const float* __restrict__ dinv,
    const float* __restrict__ bias, float* __restrict__ Out,
    int n, int half) {
    int bx = blockIdx.x;
    int chunk = bx >= half ? 1 : 0;
    int tile = bx - chunk * half;
    int t = threadIdx.x;
    int lane = t & 63;
    int g = lane >> 4;
    int q = lane & 15;
    int node = tile * 16 + (t >> 6) * 4 + g;
    bool valid = node < n;
    int nc = valid ? node : n - 1;
    int beg = row_ptr[nc], end = row_ptr[nc + 1];
    const ull_t* Tq = (const ull_t*)G + (size_t)chunk * n * 16 + q;
    float a0 = 0.f, a1 = 0.f, a2 = 0.f, a3 = 0.f;
    int e = beg;
    for (; e + 4 <= end; e += 4) {
        int s0 = srcs[e], s1 = srcs[e + 1], s2 = srcs[e + 2], s3 = srcs[e + 3];
        ull_t u0 = Tq[(size_t)s0 * 16];
        ull_t u1 = Tq[(size_t)s1 * 16];
        ull_t u2 = Tq[(size_t)s2 * 16];
        ull_t u3 = Tq[(size_t)s3 * 16];
        ACC_U(u0); ACC_U(u1); ACC_U(u2); ACC_U(u3);
    }
    for (; e < end; ++e) {
        int s = srcs[e];
        ull_t u = Tq[(size_t)s * 16];
        ACC_U(u);
    }
    if (valid) {
        float dv = dinv[node];
        const float* bp = bias + chunk * 64 + q * 4;
        f32x4 o;
        o.x = fmaf(a0, dv, bp[0]);
        o.y = fmaf(a1, dv, bp[1]);
        o.z = fmaf(a2, dv, bp[2]);
        o.w = fmaf(a3, dv, bp[3]);
        __builtin_nontemporal_store(o,
            (f32x4*)(Out + (size_t)node * 128 + chunk * 64 + q * 4));
    }
}

extern "C" void kernel_launch(void* const* d_in, const int* in_sizes, int n_in,
                              void* d_out, int out_size, void* d_ws, size_t ws_size,
                              hipStream_t stream) {
    const float* x  = (const float*)d_in[0];
    const int*   ei = (const int*)d_in[1];
    const float* W1 = (const float*)d_in[2];
    const float* b1 = (const float*)d_in[3];
    const float* W2 = (const float*)d_in[4];
    const float* b2 = (const float*)d_in[5];
    float* out = (float*)d_out;

    const int C = 128;
    const int N = in_sizes[0] / C;
    const int E = in_sizes[1] / 2;
    const int* src = ei;
    const int* dst = ei + E;
    const int total = E + N;
    const int nbp = (N + NPB - 1) >> 7;                 // buckets (782)
    const int T = (total + PART_TILE - 1) / PART_TILE;  // tiles (202)

    char* ws = (char*)d_ws;
    size_t off = 0;
    auto alloc = [&](size_t bytes) -> void* {
        void* p = ws + off;
        off = (off + bytes + 511) & ~(size_t)511;
        return p;
    };
    int*   Cmat       = (int*)alloc((size_t)T * nbp * 4);       // ~632 KB
    int*   colsum     = (int*)alloc((size_t)nbp * 4);
    int*   bucket_ptr = (int*)alloc((size_t)(nbp + 1) * 4);
    int*   row_ptr    = (int*)alloc(((size_t)N + 1) * 4);
    float* dinv       = (float*)alloc((size_t)N * 4);
    int*   srcs       = (int*)alloc((size_t)total * 4);
    ushort_t* Wp1     = (ushort_t*)alloc(128 * 128 * 2);
    ushort_t* Wp2     = (ushort_t*)alloc(128 * 128 * 2);
    ushort_t* G1      = (ushort_t*)alloc((size_t)N * C * 2);
    // act/G2 (in-place, N*C*2) shares with pairs (total*4): pairs dead
    // after k_build, act written by k_agg1 afterwards.
    size_t ab = (size_t)N * C * 2, pb = (size_t)total * 4;
    void* shared = alloc(ab > pb ? ab : pb);
    ushort_t* actG2 = (ushort_t*)shared;
    unsigned int* pairs = (unsigned int*)shared;

    // ---- radix CSR build (wprep folded into bucket_scan blocks 1..128) ----
    k_hist_tiles<<<T, 256, 0, stream>>>(dst, Cmat, E, nbp, total);
    k_col_scan<<<(nbp + 255) / 256, 256, 0, stream>>>(Cmat, colsum, T, nbp);
    k_bucket_scan<<<129, 256, 0, stream>>>(colsum, bucket_ptr, nbp, total,
                                           W1, W2, Wp1, Wp2);
    k_partition<<<T, 256, 0, stream>>>(src, dst, Cmat, bucket_ptr, pairs, E, nbp, total);
    k_build<<<nbp, 256, 0, stream>>>(pairs, bucket_ptr, row_ptr, srcs, dinv, N);

    // agg grid: two sequential halves (chunk = bx >= half), 16 nodes/block
    const int half = (N + 15) / 16;
    dim3 agrid(half * 2);

    // ---- layer 1: G1[ch][r][64] = bf16(dinv*(x@W1)); act chunked bf16 ----
    k_gemm1<<<(N + 63) / 64, 256, 0, stream>>>(x, Wp1, dinv, G1, N);
    k_agg1<<<agrid, 256, 0, stream>>>(row_ptr, srcs, G1, dinv, b1,
                                      (ull_t*)actG2, N, half);

    // ---- layer 2: G2 = bf16(dinv*(act@W2)) in-place chunked; out ----
    k_gemm2<<<(N + 63) / 64, 256, 0, stream>>>(actG2, Wp2, dinv, N);
    k_agg2<<<agrid, 256, 0, stream>>>(row_ptr, srcs, actG2, dinv, b2, out, N, half);
}